// Round 19
// baseline (53.875 us; speedup 1.0000x reference)
//
#include <hip/hip_runtime.h>

// Deformable depthwise conv1d (fp32), MI355X.
// Round 19: R15 math VERBATIM (best, 39.4us) + half-row blocks.
// R16/R17/R18 proved the ~13us non-VALU residual can't be traded into VALU
// (occupancy up = slower; LDS instrs down = slower; conflicts down = slower).
// The only zero-VALU lever left: halve the per-block serial staging prologue
// and double block granularity. Each block owns half a row + 16-float halos
// (8.3KB LDS, 2.25 staged float4/thread, grid 8192). Staging handles halos
// with a guarded load (zero outside the row) - no separate pad writes.
// Fallback (any |offs|>1, ~never taken): exact f32 path entirely from global.

constexpr int B_ = 8;
constexpr int C_ = 512;
constexpr int T_ = 4096;
constexpr int K_ = 7;
constexpr int T_OUT = T_ - K_ + 1;      // 4090
constexpr int BLOCK = 256;
constexpr int P_ = 16;                  // halo floats each side
constexpr int HALF = 2048;              // outputs (t positions) per block
constexpr int ROWP = P_ + HALF + P_;    // 2080 floats = 8320 B
constexpr int NOUT = 4;                 // consecutive outputs per thread
constexpr int SPAN = NOUT * BLOCK;      // 1024 t per iter
constexpr int NIT = HALF / SPAN;        // 2

using h2 = decltype(__builtin_amdgcn_cvt_pkrtz(0.0f, 0.0f));  // <2 x half>

__global__ __launch_bounds__(BLOCK)
void deform_dwconv1d_kernel(const float* __restrict__ x,
                            const float* __restrict__ weight,
                            const float* __restrict__ offset_w,
                            const float* __restrict__ offset_b,
                            float* __restrict__ out)
{
    __shared__ float rowp[ROWP];        // half row + halos, f32

    const int bid = blockIdx.x;
    const int bc  = bid >> 1;           // b*C + c
    const int h   = bid & 1;            // which half of the row
    const int c   = bc & (C_ - 1);
    const int tid = threadIdx.x;
    const int base = h * HALF;          // first t this block owns

    const float* xrow = x + (size_t)bc * T_;

    // ---- stage x[base-16 .. base+2064) as 520 float4 units; zero-quad
    // outside [0, T) (halos at row edges). Unit u -> global float4 G.
    {
        const float4* src4 = reinterpret_cast<const float4*>(xrow);
        float4* dst4 = reinterpret_cast<float4*>(rowp);
        const int gbase = h * (HALF / 4) - P_ / 4;   // base/4 - 4
        #pragma unroll
        for (int i = 0; i < 2; ++i) {
            const int u = tid + i * BLOCK;           // 0..511
            const int G = gbase + u;
            dst4[u] = (G >= 0 && G < T_ / 4) ? src4[G]
                                             : make_float4(0.f, 0.f, 0.f, 0.f);
        }
        if (tid < ROWP / 4 - 2 * BLOCK) {            // units 512..519
            const int u = 2 * BLOCK + tid;
            const int G = gbase + u;
            dst4[u] = (G >= 0 && G < T_ / 4) ? src4[G]
                                             : make_float4(0.f, 0.f, 0.f, 0.f);
        }
    }

    // per-channel weights: uniform indices -> scalar loads; packed f16
    // splats kept as VGPRs (R15 config; R16 showed forcing them out hurts)
    const float* owb = offset_w + c * K_ * K_;
    float ow[K_ * K_];
    #pragma unroll
    for (int i = 0; i < K_ * K_; ++i) ow[i] = owb[i];
    float wgt[K_], ob[K_];
    #pragma unroll
    for (int k = 0; k < K_; ++k) {
        wgt[k] = weight[c * K_ + k];
        ob[k]  = offset_b[c * K_ + k];
    }
    h2 owp[K_][K_], ob2[K_], wgt2[K_];
    #pragma unroll
    for (int k = 0; k < K_; ++k) {
        #pragma unroll
        for (int j = 0; j < K_; ++j)
            owp[k][j] = __builtin_amdgcn_cvt_pkrtz(ow[k * K_ + j], ow[k * K_ + j]);
        ob2[k]  = __builtin_amdgcn_cvt_pkrtz(ob[k], ob[k]);
        wgt2[k] = __builtin_amdgcn_cvt_pkrtz(wgt[k], wgt[k]);
    }

    __syncthreads();

    float* orow = out + (size_t)bc * T_OUT;
    const h2 zero2 = __builtin_bit_cast(h2, 0);

    #pragma unroll
    for (int it = 0; it < NIT; ++it) {
        const int t0 = base + it * SPAN + tid * NOUT;  // multiple of 4

        // window x[t0-4 .. t0+11] via 4x ds_read_b128 (local units)
        const float4* wp = reinterpret_cast<const float4*>(rowp) +
                           (P_ / 4 - 1 + it * BLOCK + tid);
        const float4 F0 = wp[0], F1 = wp[1], F2 = wp[2], F3 = wp[3];
        const float Wf[16] = {F0.x, F0.y, F0.z, F0.w,  F1.x, F1.y, F1.z, F1.w,
                              F2.x, F2.y, F2.z, F2.w,  F3.x, F3.y, F3.z, F3.w};
        // Wf[m] = x[t0-4+m] (zero outside [0,T-1])

        // packed window pairs Wpk[i] = {Wf[3+i], Wf[4+i]}, i=0..10
        h2 Wpk[11];
        #pragma unroll
        for (int i = 0; i < 11; ++i)
            Wpk[i] = __builtin_amdgcn_cvt_pkrtz(Wf[3 + i], Wf[4 + i]);

        // packed differences Epk[i] = Wpk[i] - Wpk[i+1]
        h2 Epk[10];
        #pragma unroll
        for (int i = 0; i < 10; ++i)
            Epk[i] = Wpk[i] - Wpk[i + 1];

        h2 acc01 = zero2, acc23 = zero2, bad2 = zero2;

        #pragma unroll
        for (int k = 0; k < K_; ++k) {
            // packed offset conv: o_r = ob + sum_j Wf[4+r+j]*ow[k][j]
            // {Wf[4+j+r], Wf[5+j+r]} = Wpk[j+1+r]
            h2 o01 = ob2[k], o23 = ob2[k];
            #pragma unroll
            for (int j = 0; j < K_; ++j) {
                o01 = __builtin_elementwise_fma(Wpk[j + 1], owp[k][j], o01);
                o23 = __builtin_elementwise_fma(Wpk[j + 3], owp[k][j], o23);
            }

            bad2 = __builtin_elementwise_max(bad2, __builtin_elementwise_abs(o01));
            bad2 = __builtin_elementwise_max(bad2, __builtin_elementwise_abs(o23));

            // packed branchless 3-tap stencil (exact for |o| <= 1):
            // s_r = Wf[4+r+k] + an*E[3+r+k] - cn*E[4+r+k]
            const h2 an01 = __builtin_elementwise_max(-o01, zero2);
            const h2 cn01 = __builtin_elementwise_max(o01, zero2);
            const h2 an23 = __builtin_elementwise_max(-o23, zero2);
            const h2 cn23 = __builtin_elementwise_max(o23, zero2);

            h2 s01 = __builtin_elementwise_fma(an01, Epk[k],      Wpk[k + 1]);
            s01    = __builtin_elementwise_fma(cn01, -Epk[k + 1], s01);
            h2 s23 = __builtin_elementwise_fma(an23, Epk[k + 2],  Wpk[k + 3]);
            s23    = __builtin_elementwise_fma(cn23, -Epk[k + 3], s23);

            acc01 = __builtin_elementwise_fma(wgt2[k], s01, acc01);
            acc23 = __builtin_elementwise_fma(wgt2[k], s23, acc23);
        }

        float acc[NOUT] = {(float)acc01.x, (float)acc01.y,
                           (float)acc23.x, (float)acc23.y};

        // exact fallback (wave-uniform, ~never taken): any |offs| > 1 ->
        // full f32 recompute from GLOBAL (validity-masked gathers,
        // reference semantics: zero outside [0, T-1]).
        const float badf = fmaxf((float)bad2.x, (float)bad2.y);
        if (__any(badf > 1.0f)) {
            #pragma unroll
            for (int r = 0; r < NOUT; ++r) {
                float a2 = 0.0f;
                #pragma unroll
                for (int k = 0; k < K_; ++k) {
                    float v = ob[k];
                    #pragma unroll
                    for (int j = 0; j < K_; ++j) {
                        const int xi = min(t0 + r + j, T_ - 1);  // clamps only
                        v = fmaf(xrow[xi], ow[k * K_ + j], v);   // discarded rows
                    }
                    const float pos = (float)(t0 + r + k) + v;
                    const float fl  = floorf(pos);
                    const int   i0  = (int)fl;
                    const float u   = pos - fl;
                    const int c0 = min(max(i0, 0), T_ - 1);
                    const int c1 = min(max(i0 + 1, 0), T_ - 1);
                    float g0 = xrow[c0];
                    float g1 = xrow[c1];
                    if (i0 < 0 || i0 > T_ - 1) g0 = 0.0f;
                    if (i0 + 1 < 0 || i0 + 1 > T_ - 1) g1 = 0.0f;
                    a2 = fmaf(fmaf(u, g1 - g0, g0), wgt[k], a2);
                }
                acc[r] = a2;
            }
        }

        // stores: two 8B-aligned float2 per thread; runtime tail guards
        // (only the last iter of the h=1 block can fail them)
        if (t0 + 1 < T_OUT)
            *reinterpret_cast<float2*>(orow + t0)     = make_float2(acc[0], acc[1]);
        if (t0 + 3 < T_OUT)
            *reinterpret_cast<float2*>(orow + t0 + 2) = make_float2(acc[2], acc[3]);
    }
}

extern "C" void kernel_launch(void* const* d_in, const int* in_sizes, int n_in,
                              void* d_out, int out_size, void* d_ws, size_t ws_size,
                              hipStream_t stream) {
    const float* x        = (const float*)d_in[0];
    const float* weight   = (const float*)d_in[1];
    const float* offset_w = (const float*)d_in[2];
    const float* offset_b = (const float*)d_in[3];
    float* out = (float*)d_out;

    deform_dwconv1d_kernel<<<B_ * C_ * 2, BLOCK, 0, stream>>>(
        x, weight, offset_w, offset_b, out);
}

// Round 20
// 39.293 us; speedup vs baseline: 1.3711x; 1.3711x over previous
//
#include <hip/hip_runtime.h>

// Deformable depthwise conv1d (fp32), MI355X.
// Round 20: REVERT to R15 verbatim (best: 39.4us).
// R16-R19 completed the factorial around this configuration: raising
// occupancy (R16), cutting LDS instrs (R17), cutting bank conflicts (R18),
// and halving the staging prologue (R19) each moved their targeted counter
// exactly as predicted and REGRESSED dur (+3.4/+5.5/+6.7/+14.5 us), because
// each paid in VALU ops or register pressure. R15 is a balanced multi-pipe
// equilibrium: VALU ~25us busy (largest pipe), LDS ~13us overlapped, HBM 29%,
// occupancy-insensitive. This round re-establishes it; if reproduced, this
// is the practical floor.

constexpr int B_ = 8;
constexpr int C_ = 512;
constexpr int T_ = 4096;
constexpr int K_ = 7;
constexpr int T_OUT = T_ - K_ + 1;      // 4090
constexpr int BLOCK = 256;
constexpr int P_ = 16;                  // zero pad each side
constexpr int ROWP = P_ + T_ + P_;      // 4128 floats = 16.5 KB
constexpr int NOUT = 4;                 // consecutive outputs per thread
constexpr int SPAN = NOUT * BLOCK;      // 1024 t per iter
constexpr int NIT = 4;

using h2 = decltype(__builtin_amdgcn_cvt_pkrtz(0.0f, 0.0f));  // <2 x half>

__device__ __forceinline__ float fract_f(float p) {
#if __has_builtin(__builtin_amdgcn_fractf)
    return __builtin_amdgcn_fractf(p);
#else
    return p - floorf(p);
#endif
}

__device__ __forceinline__ float clamp01hi(float a, float hi) {
#if __has_builtin(__builtin_amdgcn_fmed3f)
    return __builtin_amdgcn_fmed3f(a, 0.0f, hi);
#else
    return fminf(fmaxf(a, 0.0f), hi);
#endif
}

__global__ __launch_bounds__(BLOCK)
void deform_dwconv1d_kernel(const float* __restrict__ x,
                            const float* __restrict__ weight,
                            const float* __restrict__ offset_w,
                            const float* __restrict__ offset_b,
                            float* __restrict__ out)
{
    __shared__ float rowp[ROWP];

    const int bc  = blockIdx.x;        // b*C + c
    const int c   = bc & (C_ - 1);
    const int tid = threadIdx.x;

    if (tid < P_) {
        rowp[tid] = 0.0f;
        rowp[P_ + T_ + tid] = 0.0f;
    }

    const float* xrow = x + (size_t)bc * T_;
    const float4* src = reinterpret_cast<const float4*>(xrow);
    float4* dst = reinterpret_cast<float4*>(rowp + P_);
    #pragma unroll
    for (int i = 0; i < T_ / 4 / BLOCK; ++i)
        dst[tid + i * BLOCK] = src[tid + i * BLOCK];

    // per-channel weights: uniform indices -> scalar (SGPR) loads
    float ow[K_ * K_];
    #pragma unroll
    for (int i = 0; i < K_ * K_; ++i) ow[i] = offset_w[c * K_ * K_ + i];
    float wgt[K_], ob[K_];
    #pragma unroll
    for (int k = 0; k < K_; ++k) {
        wgt[k] = weight[c * K_ + k];
        ob[k]  = offset_b[c * K_ + k];
    }

    // packed (splat) f16 weights, uniform -> scalar regs
    h2 owp[K_][K_], ob2[K_], wgt2[K_];
    #pragma unroll
    for (int k = 0; k < K_; ++k) {
        #pragma unroll
        for (int j = 0; j < K_; ++j)
            owp[k][j] = __builtin_amdgcn_cvt_pkrtz(ow[k * K_ + j], ow[k * K_ + j]);
        ob2[k]  = __builtin_amdgcn_cvt_pkrtz(ob[k], ob[k]);
        wgt2[k] = __builtin_amdgcn_cvt_pkrtz(wgt[k], wgt[k]);
    }

    __syncthreads();

    float* orow = out + (size_t)bc * T_OUT;
    constexpr float HI = (float)(ROWP - 2);
    const h2 zero2 = __builtin_amdgcn_cvt_pkrtz(0.0f, 0.0f);

    #pragma unroll
    for (int it = 0; it < NIT; ++it) {
        const int t0 = it * SPAN + tid * NOUT;   // multiple of 4, max 4092

        // window x[t0-4 .. t0+11] via 4x ds_read_b128
        const float4* wp = reinterpret_cast<const float4*>(rowp + (P_ - 4) + t0);
        const float4 F0 = wp[0], F1 = wp[1], F2 = wp[2], F3 = wp[3];
        const float Wf[16] = {F0.x, F0.y, F0.z, F0.w,  F1.x, F1.y, F1.z, F1.w,
                              F2.x, F2.y, F2.z, F2.w,  F3.x, F3.y, F3.z, F3.w};
        // Wf[m] = x[t0-4+m]

        // packed window pairs Wpk[i] = {Wf[3+i], Wf[4+i]}, i=0..10
        h2 Wpk[11];
        #pragma unroll
        for (int i = 0; i < 11; ++i)
            Wpk[i] = __builtin_amdgcn_cvt_pkrtz(Wf[3 + i], Wf[4 + i]);

        // packed differences Epk[i] = Wpk[i] - Wpk[i+1]
        h2 Epk[10];
        #pragma unroll
        for (int i = 0; i < 10; ++i)
            Epk[i] = Wpk[i] - Wpk[i + 1];

        h2 acc01 = zero2, acc23 = zero2, bad2 = zero2;

        #pragma unroll
        for (int k = 0; k < K_; ++k) {
            // packed offset conv: o_r = ob + sum_j Wf[4+r+j]*ow[k][j]
            // {Wf[4+j+r], Wf[5+j+r]} = Wpk[j+1+r]
            h2 o01 = ob2[k], o23 = ob2[k];
            #pragma unroll
            for (int j = 0; j < K_; ++j) {
                o01 = __builtin_elementwise_fma(Wpk[j + 1], owp[k][j], o01);
                o23 = __builtin_elementwise_fma(Wpk[j + 3], owp[k][j], o23);
            }

            bad2 = __builtin_elementwise_max(bad2, __builtin_elementwise_abs(o01));
            bad2 = __builtin_elementwise_max(bad2, __builtin_elementwise_abs(o23));

            // packed branchless 3-tap stencil (exact for |o| <= 1):
            // s_r = Wf[4+r+k] + an*E[3+r+k] - cn*E[4+r+k]
            const h2 an01 = __builtin_elementwise_max(-o01, zero2);
            const h2 cn01 = __builtin_elementwise_max(o01, zero2);
            const h2 an23 = __builtin_elementwise_max(-o23, zero2);
            const h2 cn23 = __builtin_elementwise_max(o23, zero2);

            h2 s01 = __builtin_elementwise_fma(an01, Epk[k],      Wpk[k + 1]);
            s01    = __builtin_elementwise_fma(cn01, -Epk[k + 1], s01);
            h2 s23 = __builtin_elementwise_fma(an23, Epk[k + 2],  Wpk[k + 3]);
            s23    = __builtin_elementwise_fma(cn23, -Epk[k + 3], s23);

            acc01 = __builtin_elementwise_fma(wgt2[k], s01, acc01);
            acc23 = __builtin_elementwise_fma(wgt2[k], s23, acc23);
        }

        float acc[NOUT] = {(float)acc01.x, (float)acc01.y,
                           (float)acc23.x, (float)acc23.y};

        // exact fallback (wave-uniform, ~never taken): any |offs| > 1 ->
        // redo all 4 outputs via the clamped padded-LDS gather path (f32).
        const float badf = fmaxf((float)bad2.x, (float)bad2.y);
        if (__any(badf > 1.0f)) {
            #pragma unroll
            for (int r = 0; r < NOUT; ++r) {
                float a2 = 0.0f;
                const float tf = (float)(t0 + r + P_);
                #pragma unroll
                for (int k = 0; k < K_; ++k) {
                    float v = ob[k];
                    #pragma unroll
                    for (int j = 0; j < K_; ++j)
                        v = fmaf(Wf[4 + r + j], ow[k * K_ + j], v);
                    const float p  = clamp01hi(v + tf + (float)k, HI);
                    const int   i0 = (int)p;
                    const float u  = fract_f(p);
                    const float g0 = rowp[i0], g1 = rowp[i0 + 1];
                    a2 = fmaf(fmaf(u, g1 - g0, g0), wgt[k], a2);
                }
                acc[r] = a2;
            }
        }

        // stores: two 8B-aligned float2 per thread; guards only in the tail
        if (it < NIT - 1) {
            *reinterpret_cast<float2*>(orow + t0)     = make_float2(acc[0], acc[1]);
            *reinterpret_cast<float2*>(orow + t0 + 2) = make_float2(acc[2], acc[3]);
        } else {
            if (t0 + 1 < T_OUT)
                *reinterpret_cast<float2*>(orow + t0)     = make_float2(acc[0], acc[1]);
            if (t0 + 3 < T_OUT)
                *reinterpret_cast<float2*>(orow + t0 + 2) = make_float2(acc[2], acc[3]);
        }
    }
}

extern "C" void kernel_launch(void* const* d_in, const int* in_sizes, int n_in,
                              void* d_out, int out_size, void* d_ws, size_t ws_size,
                              hipStream_t stream) {
    const float* x        = (const float*)d_in[0];
    const float* weight   = (const float*)d_in[1];
    const float* offset_w = (const float*)d_in[2];
    const float* offset_b = (const float*)d_in[3];
    float* out = (float*)d_out;

    deform_dwconv1d_kernel<<<B_ * C_, BLOCK, 0, stream>>>(
        x, weight, offset_w, offset_b, out);
}